// Round 6
// baseline (160.164 us; speedup 1.0000x reference)
//
#include <hip/hip_runtime.h>
#include <stdint.h>

#define NROW 4096
#define NDIM 128
#define KNEG 4092
#define INF_VAL 1e30f
#define BUCKETS 2048
#define DISTBLKS 1024                         // 32x32 tiles of 128x128

typedef __attribute__((ext_vector_type(8))) short short8;
typedef __attribute__((ext_vector_type(4))) float f32x4;

// ---------------- Threefry-2x32-20, key = (0, 42) ----------------
__device__ __forceinline__ uint32_t rotl32(uint32_t v, int d) {
  return __builtin_rotateleft32(v, (unsigned)d);
}

__device__ __forceinline__ void threefry2x32(uint32_t x0, uint32_t x1,
                                             uint32_t& y0, uint32_t& y1) {
  const uint32_t k0 = 0u, k1 = 42u;
  const uint32_t k2 = 0x1BD11BDAu ^ k0 ^ k1;
  uint32_t v0 = x0 + k0, v1 = x1 + k1;
#define TF_R(r) v0 += v1; v1 = rotl32(v1, r); v1 ^= v0;
  TF_R(13) TF_R(15) TF_R(26) TF_R(6)
  v0 += k1; v1 += k2 + 1u;
  TF_R(17) TF_R(29) TF_R(16) TF_R(24)
  v0 += k2; v1 += k0 + 2u;
  TF_R(13) TF_R(15) TF_R(26) TF_R(6)
  v0 += k0; v1 += k1 + 3u;
  TF_R(17) TF_R(29) TF_R(16) TF_R(24)
  v0 += k1; v1 += k2 + 4u;
  TF_R(13) TF_R(15) TF_R(26) TF_R(6)
  v0 += k2; v1 += k0 + 5u;
#undef TF_R
  y0 = v0; y1 = v1;
}

__device__ __forceinline__ float gumbel_ref(uint32_t f) {
  uint32_t y0, y1;
  threefry2x32(0u, f, y0, y1);
  uint32_t m = y1 >> 9;
  float fm = (float)m;                                     // exact (m < 2^24)
  float nl = fmaf(-0.69314718f, __log2f(fm), 15.942385f);  // ln2*(23-log2 m)
  if (m == 0u) nl = 87.33655f;                             // -log(tiny)
  return -0.69314718f * __log2f(nl);
}

__device__ __forceinline__ float softplus_ref(float x) {
  return fmaxf(x, 0.0f) + log1pf(expf(-fabsf(x)));
}

__device__ __forceinline__ ushort f2h(float f) {
  _Float16 h = (_Float16)f;
  return *(ushort*)&h;
}
__device__ __forceinline__ float h2f(ushort u) {
  _Float16 h = *(_Float16*)&u;
  return (float)h;
}
__device__ __forceinline__ float bf2f(ushort u) {
  return __uint_as_float(((uint32_t)u) << 16);
}
__device__ __forceinline__ ushort f2bf(float f) {
  uint32_t u = __float_as_uint(f);
  u += 0x7fffu + ((u >> 16) & 1u);
  return (ushort)(u >> 16);
}

// fp16-roundtripped gumbel — BIT-IDENTICAL to the old table path.
__device__ __forceinline__ float gumbel_h2f(uint32_t f) {
  return h2f(f2h(gumbel_ref(f)));
}

// bucket = bf16 code (monotone & injective for positive floats); every bucket
// holds only exactly-equal values => scatter position IS the exact rank.
__device__ __forceinline__ int bucket_code(ushort code) {
  return min(max((int)code - 0x4000, 0), BUCKETS - 1);
}

// monotone u32 key for f32 (total order, matches > on non-NaN floats)
__device__ __forceinline__ uint32_t fkey(float f) {
  uint32_t b = __float_as_uint(f);
  return b ^ ((uint32_t)((int32_t)b >> 31) | 0x80000000u);
}

// branchless insert into sorted-descending u64 triple with f32 payload
__device__ __forceinline__ void ins3p(uint64_t v, float s,
                                      uint64_t& t0, float& s0,
                                      uint64_t& t1, float& s1,
                                      uint64_t& t2, float& s2) {
  bool c0 = v > t0, c1 = v > t1, c2 = v > t2;
  t2 = c1 ? t1 : (c2 ? v : t2); s2 = c1 ? s1 : (c2 ? s : s2);
  t1 = c0 ? t0 : (c1 ? v : t1); s1 = c0 ? s0 : (c1 ? s : s1);
  t0 = c0 ? v : t0;             s0 = c0 ? s : s0;
}

// merge two sorted-descending triples (with f32 payload) -> top-3 in a*
__device__ __forceinline__ void merge3p(uint64_t& a0, float& p0,
                                        uint64_t& a1, float& p1,
                                        uint64_t& a2, float& p2,
                                        uint64_t b0, float q0,
                                        uint64_t b1, float q1,
                                        uint64_t b2, float q2) {
  bool sw = b0 > a0;
  uint64_t n0 = sw ? b0 : a0; float n0p = sw ? q0 : p0;
  uint64_t m0 = sw ? a0 : b0; float m0p = sw ? p0 : q0;
  uint64_t n1 = sw ? b1 : a1; float n1p = sw ? q1 : p1;
  uint64_t m1 = sw ? a1 : b1; float m1p = sw ? p1 : q1;
  uint64_t n2 = sw ? b2 : a2; float n2p = sw ? q2 : p2;
  a0 = n0; p0 = n0p;
  bool c = n1 > m0;  // keys distinct (unique ranks)
  a1 = c ? n1 : m0;  p1 = c ? n1p : m0p;
  uint64_t u = c ? n2 : n1; float up = c ? n2p : n1p;
  uint64_t w = c ? m0 : m1; float wp = c ? m0p : m1p;
  bool d = u > w;
  a2 = d ? u : w; p2 = d ? up : wp;
}

// ---------------- kernel A: sumsq + fp32->bf16 convert (4 rows/block) -------
__global__ __launch_bounds__(256) void prep_kernel(const float* __restrict__ X,
                                                   float* __restrict__ sq,
                                                   ushort* __restrict__ Xbf) {
  const int tid = threadIdx.x;
  const int lane = tid & 63;
  const int i = (blockIdx.x << 2) + (tid >> 6);
  float2 v = ((const float2*)(X + (size_t)i * NDIM))[lane];
  float s = v.x * v.x + v.y * v.y;
  for (int o = 32; o > 0; o >>= 1) s += __shfl_down(s, o);
  if (lane == 0) sq[i] = s;
  ushort2 h;
  h.x = f2bf(v.x);
  h.y = f2bf(v.y);
  ((ushort2*)(Xbf + (size_t)i * NDIM))[lane] = h;
}

// ---------------- kernel B: dist tile per block — LDS-FREE ------------------
// Operands total 64 KB/block and Xbf (1 MB) is L2-resident on every XCD, so
// MFMA fragments are read DIRECTLY from global (L2): per fragment instruction
// a wave touches 16 rows x 64B contiguous — good L2 coalescing. No LDS, no
// barriers, no staging VALU. Accumulation chain (kh -> k0 -> mfma) identical
// to the staged version and fragment bytes identical => bit-identical distb.
__global__ __launch_bounds__(256) void dist_kernel(const ushort* __restrict__ Xbf,
                                                   const float* __restrict__ sq,
                                                   ushort* __restrict__ distb) {
  const int tid = threadIdx.x;
  const int bi = blockIdx.x >> 5, bj = blockIdx.x & 31;
  const int wave = tid >> 6, lane = tid & 63;
  const int q = lane >> 4, ln = lane & 15;
  const ushort* Ag = Xbf + (size_t)bi * 128 * NDIM;
  const ushort* Bg = Xbf + (size_t)bj * 128 * NDIM;

  f32x4 acc[8][2];
#pragma unroll
  for (int mt = 0; mt < 8; ++mt)
#pragma unroll
    for (int nt = 0; nt < 2; ++nt) acc[mt][nt] = (f32x4){0.f, 0.f, 0.f, 0.f};

  const int browA = ln;                      // + mt*16
  const int browB = wave * 32 + 2 * ln;      // + nt

  for (int kh = 0; kh < 2; ++kh) {
#pragma unroll
    for (int k0 = 0; k0 < 64; k0 += 32) {
      const int kf = kh * 64 + k0 + q * 8;   // global k-offset of this slice
      short8 a[8], b[2];
#pragma unroll
      for (int mt = 0; mt < 8; ++mt)
        a[mt] = *(const short8*)(Ag + (size_t)(mt * 16 + browA) * NDIM + kf);
#pragma unroll
      for (int nt = 0; nt < 2; ++nt)
        b[nt] = *(const short8*)(Bg + (size_t)(browB + nt) * NDIM + kf);
#pragma unroll
      for (int mt = 0; mt < 8; ++mt)
#pragma unroll
        for (int nt = 0; nt < 2; ++nt)
          acc[mt][nt] = __builtin_amdgcn_mfma_f32_16x16x32_bf16(
              a[mt], b[nt], acc[mt][nt], 0, 0, 0);
    }
  }

  const int jcol = bj * 128 + wave * 32 + 2 * ln;
  float sqj0 = sq[jcol], sqj1 = sq[jcol + 1];
#pragma unroll
  for (int mt = 0; mt < 8; ++mt) {
    int ibase = bi * 128 + mt * 16 + q * 4;
#pragma unroll
    for (int r = 0; r < 4; ++r) {
      int i = ibase + r;
      float sqi = sq[i];
      float dx = sqrtf(fmaxf(sqi + sqj0 - 2.0f * acc[mt][0][r], 1e-12f));
      float dy = sqrtf(fmaxf(sqi + sqj1 - 2.0f * acc[mt][1][r], 1e-12f));
      uint32_t pack = ((uint32_t)f2bf(dy) << 16) | (uint32_t)f2bf(dx);
      *(uint32_t*)(distb + (size_t)i * NROW + jcol) = pack;
    }
  }
}

// ---------------- kernel C: per-row rank + sample + loss --------------------
// Direct-rank scoring (R5): p = base[bkt] + ord; gumbel inline (bit-identical
// fp16 roundtrip); u64 (score,rank) keys; single-pass block top-3.
__global__ __launch_bounds__(256) void row_kernel(const ushort* __restrict__ distb,
                                                  float4* __restrict__ part) {
  __shared__ alignas(16) int base[BUCKETS];    // 8 KB (bucket starts)
  __shared__ alignas(16) float candx[768];     // 3 KB payload
  __shared__ float wredf[8];
  __shared__ int wtot[4];
  __shared__ float s_pos[3];
  __shared__ float s_selx[3];

  // alias — live only after the score pass (base dead after its last read)
  uint64_t* cand = (uint64_t*)base;            // 768 * 8B = 6 KB

  const int i = blockIdx.x;
  const int tid = threadIdx.x;
  const int lane = tid & 63, wid = tid >> 6;
  const ushort* row = distb + (size_t)i * NROW;
  const int gbase = i & ~3;
  const uint32_t fbase = (uint32_t)i * (uint32_t)KNEG;

  {
    int4* b4 = (int4*)base;
    b4[tid] = (int4){0, 0, 0, 0};
    b4[tid + 256] = (int4){0, 0, 0, 0};
  }

  short8 r0 = *(const short8*)(row + tid * 16);
  short8 r1 = *(const short8*)(row + tid * 16 + 8);

  ushort cd[16];
  float x[16];
#pragma unroll
  for (int k = 0; k < 8; ++k) {
    cd[k] = (ushort)r0[k];     x[k] = bf2f(cd[k]);
    cd[8 + k] = (ushort)r1[k]; x[8 + k] = bf2f(cd[8 + k]);
  }

  if (tid == (gbase >> 4)) {
    float p[3]; int np = 0;
#pragma unroll
    for (int qq = 0; qq < 4; ++qq) {
      int j = gbase + qq;
      if (j != i) p[np++] = x[j & 15];
    }
    float a = p[0], b = p[1], c = p[2], t_;
    if (a > b) { t_ = a; a = b; b = t_; }
    if (b > c) { t_ = b; b = c; c = t_; }
    if (a > b) { t_ = a; a = b; b = t_; }
    s_pos[0] = a; s_pos[1] = b; s_pos[2] = c;
  }

#pragma unroll
  for (int qq = 0; qq < 16; ++qq) {
    int j = tid * 16 + qq;
    if ((j >> 2) == (i >> 2)) { x[qq] = INF_VAL; cd[qq] = 0x7F80u; }
  }
  __syncthreads();

  int bkt[16];
  int ord[16];
  float ls = 0.f;
#pragma unroll
  for (int qq = 0; qq < 16; ++qq) {
    bkt[qq] = bucket_code(cd[qq]);
    ord[qq] = atomicAdd(&base[bkt[qq]], 1);
    if (x[qq] < 1e29f) ls += x[qq];
  }
  for (int o = 32; o > 0; o >>= 1) ls += __shfl_down(ls, o);
  if (lane == 0) wredf[wid] = ls;
  __syncthreads();
  const float negsum = wredf[0] + wredf[1] + wredf[2] + wredf[3];
  const float mean = negsum / (float)KNEG;

  int c8[8]; int lsum = 0;
#pragma unroll
  for (int qq = 0; qq < 8; ++qq) {
    int t_ = base[tid * 8 + qq];
    c8[qq] = lsum; lsum += t_;
  }
  float ls2 = 0.f;
#pragma unroll
  for (int qq = 0; qq < 16; ++qq)
    if (x[qq] < 1e29f) { float z = x[qq] - mean; ls2 += z * z; }
  int incl = lsum;
  for (int off = 1; off < 64; off <<= 1) {
    int o = __shfl_up(incl, off);
    if (lane >= off) incl += o;
  }
  for (int o = 32; o > 0; o >>= 1) ls2 += __shfl_down(ls2, o);
  if (lane == 63) wtot[wid] = incl;
  if (lane == 0) wredf[4 + wid] = ls2;
  __syncthreads();
  const float var = (wredf[4] + wredf[5] + wredf[6] + wredf[7]) / (float)KNEG;
  const float stdv = sqrtf(var);
  const float rdenom = __frcp_rn(2.0f * stdv * stdv);
  int excl = incl - lsum;
#pragma unroll
  for (int w = 0; w < 4; ++w) if (w < wid) excl += wtot[w];
#pragma unroll
  for (int qq = 0; qq < 8; ++qq) base[tid * 8 + qq] = excl + c8[qq];
  __syncthreads();

  // ---- score/top-3 directly from registers: p = base[bkt] + ord ----
  uint64_t t0 = 0, t1 = 0, t2 = 0;  // 0 < key of any real candidate
  float t0x = 0.f, t1x = 0.f, t2x = 0.f;
#pragma unroll
  for (int qq = 0; qq < 16; ++qq) {
    if (x[qq] < 1e29f) {                       // reals == ranks 0..KNEG-1
      int p = base[bkt[qq]] + ord[qq];
      float xv = x[qq];
      float z = xv - mean;
      float gv = gumbel_h2f(fbase + (uint32_t)p);
      float sv = fmaf(z * z, rdenom, gv);
      uint64_t v = ((uint64_t)fkey(sv) << 32) | (uint32_t)(8192 - p);
      ins3p(v, xv, t0, t0x, t1, t1x, t2, t2x);
    }
  }
  __syncthreads();  // base reads done; cand alias becomes live

  cand[tid * 3 + 0] = t0; candx[tid * 3 + 0] = t0x;
  cand[tid * 3 + 1] = t1; candx[tid * 3 + 1] = t1x;
  cand[tid * 3 + 2] = t2; candx[tid * 3 + 2] = t2x;
  __syncthreads();

  // ---- single-pass block top-3: wave 0 scans 768 + shfl_xor triple-merge ---
  if (wid == 0) {
    uint64_t a0 = 0, a1 = 0, a2 = 0;
    int i0 = 0, i1 = 0, i2 = 0;
#pragma unroll
    for (int k = 0; k < 12; ++k) {
      int idx = lane + 64 * k;
      uint64_t v = cand[idx];
      bool c0 = v > a0, c1 = v > a1, c2 = v > a2;
      a2 = c1 ? a1 : (c2 ? v : a2); i2 = c1 ? i1 : (c2 ? idx : i2);
      a1 = c0 ? a0 : (c1 ? v : a1); i1 = c0 ? i0 : (c1 ? idx : i1);
      a0 = c0 ? v : a0;             i0 = c0 ? idx : i0;
    }
    float p0 = candx[i0], p1 = candx[i1], p2 = candx[i2];
#pragma unroll
    for (int m = 32; m > 0; m >>= 1) {
      uint64_t b0 = __shfl_xor((unsigned long long)a0, m);
      uint64_t b1 = __shfl_xor((unsigned long long)a1, m);
      uint64_t b2 = __shfl_xor((unsigned long long)a2, m);
      float q0 = __shfl_xor(p0, m);
      float q1 = __shfl_xor(p1, m);
      float q2 = __shfl_xor(p2, m);
      merge3p(a0, p0, a1, p1, a2, p2, b0, q0, b1, q1, b2, q2);
    }
    if (lane == 0) {
      s_selx[0] = p0; s_selx[1] = p1; s_selx[2] = p2;
    }
  }
  __syncthreads();

  if (tid == 0) {
    float p0 = s_pos[0], p1 = s_pos[1], p2 = s_pos[2];
    float thr = p2 + 0.05f;
    float samp[3]; bool kept[3]; int cnt = 0;
#pragma unroll
    for (int t = 0; t < 3; ++t) {
      samp[t] = s_selx[t];
      kept[t] = samp[t] < thr;
      cnt += kept[t] ? 1 : 0;
    }
    bool any = cnt > 0;
    float pos_loss = 0.5f *
        (softplus_ref(-2.0f * (1.0f - p0)) + softplus_ref(-2.0f * (1.0f - p1)) +
         softplus_ref(-2.0f * (1.0f - p2))) / 3.0f;
    float nsum = 0.0f;
#pragma unroll
    for (int t = 0; t < 3; ++t)
      if (kept[t]) nsum += softplus_ref(20.0f * (1.0f - samp[t]));
    float neg_loss = 0.05f * nsum / (float)(cnt > 0 ? cnt : 1);
    float row_loss = any ? (pos_loss + neg_loss) : 0.0f;
    int first = kept[0] ? 0 : (kept[1] ? 1 : (kept[2] ? 2 : 0));
    float neg0 = samp[first];
    float errv = (any && (p0 < neg0 - 0.1f)) ? 1.0f : 0.0f;
    float4 pr;
    pr.x = row_loss; pr.y = errv; pr.z = p0 + p1 + p2; pr.w = negsum;
    part[i] = pr;
  }
}

// ---------------- reduce: 4096 float4 partials -> 4 outputs ----------------
__global__ __launch_bounds__(256) void reduce_kernel(const float4* __restrict__ part,
                                                     float* __restrict__ out) {
  __shared__ double wsum[4][4];
  const int tid = threadIdx.x;
  const int lane = tid & 63, wid = tid >> 6;
  double s0 = 0.0, s1 = 0.0, s2 = 0.0, s3 = 0.0;
  for (int k = tid; k < NROW; k += 256) {
    float4 v = part[k];
    s0 += (double)v.x; s1 += (double)v.y; s2 += (double)v.z; s3 += (double)v.w;
  }
  for (int o = 32; o > 0; o >>= 1) {
    s0 += __shfl_down(s0, o); s1 += __shfl_down(s1, o);
    s2 += __shfl_down(s2, o); s3 += __shfl_down(s3, o);
  }
  if (lane == 0) {
    wsum[wid][0] = s0; wsum[wid][1] = s1; wsum[wid][2] = s2; wsum[wid][3] = s3;
  }
  __syncthreads();
  if (tid == 0) {
    double a0 = wsum[0][0] + wsum[1][0] + wsum[2][0] + wsum[3][0];
    double a1 = wsum[0][1] + wsum[1][1] + wsum[2][1] + wsum[3][1];
    double a2 = wsum[0][2] + wsum[1][2] + wsum[2][2] + wsum[3][2];
    double a3 = wsum[0][3] + wsum[1][3] + wsum[2][3] + wsum[3][3];
    out[0] = (float)(a0 / (double)NROW);
    out[1] = (float)(1.0 - a1 / (double)NROW);
    out[2] = (float)(a2 / ((double)NROW * 3.0));
    out[3] = (float)(a3 / ((double)NROW * (double)KNEG));
  }
}

extern "C" void kernel_launch(void* const* d_in, const int* in_sizes, int n_in,
                              void* d_out, int out_size, void* d_ws, size_t ws_size,
                              hipStream_t stream) {
  (void)in_sizes; (void)n_in; (void)out_size; (void)ws_size;
  const float* X = (const float*)d_in[0];
  float* out = (float*)d_out;
  char* ws = (char*)d_ws;

  ushort* distb = (ushort*)ws;                                     // 32 MiB bf16
  size_t off = (size_t)NROW * NROW * sizeof(ushort);
  float* sq = (float*)(ws + off);            off += NROW * sizeof(float);
  ushort* Xbf = (ushort*)(ws + off);         off += (size_t)NROW * NDIM * sizeof(ushort);
  float4* part = (float4*)(ws + off);        off += (size_t)NROW * sizeof(float4);

  prep_kernel<<<NROW / 4, 256, 0, stream>>>(X, sq, Xbf);
  dist_kernel<<<DISTBLKS, 256, 0, stream>>>(Xbf, sq, distb);
  row_kernel<<<NROW, 256, 0, stream>>>(distb, part);
  reduce_kernel<<<1, 256, 0, stream>>>(part, out);
}

// Round 7
// 148.005 us; speedup vs baseline: 1.0822x; 1.0822x over previous
//
#include <hip/hip_runtime.h>
#include <stdint.h>

#define NROW 4096
#define NDIM 128
#define KNEG 4092
#define INF_VAL 1e30f
#define BUCKETS 2048
#define DISTBLKS 2048                         // 64x128 tiles: 64 bi x 32 bj
#define DSTR 68

typedef __attribute__((ext_vector_type(8))) short short8;
typedef __attribute__((ext_vector_type(4))) float f32x4;

// ---------------- Threefry-2x32-20, key = (0, 42) ----------------
__device__ __forceinline__ uint32_t rotl32(uint32_t v, int d) {
  return __builtin_rotateleft32(v, (unsigned)d);
}

__device__ __forceinline__ void threefry2x32(uint32_t x0, uint32_t x1,
                                             uint32_t& y0, uint32_t& y1) {
  const uint32_t k0 = 0u, k1 = 42u;
  const uint32_t k2 = 0x1BD11BDAu ^ k0 ^ k1;
  uint32_t v0 = x0 + k0, v1 = x1 + k1;
#define TF_R(r) v0 += v1; v1 = rotl32(v1, r); v1 ^= v0;
  TF_R(13) TF_R(15) TF_R(26) TF_R(6)
  v0 += k1; v1 += k2 + 1u;
  TF_R(17) TF_R(29) TF_R(16) TF_R(24)
  v0 += k2; v1 += k0 + 2u;
  TF_R(13) TF_R(15) TF_R(26) TF_R(6)
  v0 += k0; v1 += k1 + 3u;
  TF_R(17) TF_R(29) TF_R(16) TF_R(24)
  v0 += k1; v1 += k2 + 4u;
  TF_R(13) TF_R(15) TF_R(26) TF_R(6)
  v0 += k2; v1 += k0 + 5u;
#undef TF_R
  y0 = v0; y1 = v1;
}

__device__ __forceinline__ float gumbel_ref(uint32_t f) {
  uint32_t y0, y1;
  threefry2x32(0u, f, y0, y1);
  uint32_t m = y1 >> 9;
  float fm = (float)m;                                     // exact (m < 2^24)
  float nl = fmaf(-0.69314718f, __log2f(fm), 15.942385f);  // ln2*(23-log2 m)
  if (m == 0u) nl = 87.33655f;                             // -log(tiny)
  return -0.69314718f * __log2f(nl);
}

__device__ __forceinline__ float softplus_ref(float x) {
  return fmaxf(x, 0.0f) + log1pf(expf(-fabsf(x)));
}

__device__ __forceinline__ ushort f2h(float f) {
  _Float16 h = (_Float16)f;
  return *(ushort*)&h;
}
__device__ __forceinline__ float h2f(ushort u) {
  _Float16 h = *(_Float16*)&u;
  return (float)h;
}
__device__ __forceinline__ float bf2f(ushort u) {
  return __uint_as_float(((uint32_t)u) << 16);
}
__device__ __forceinline__ ushort f2bf(float f) {
  uint32_t u = __float_as_uint(f);
  u += 0x7fffu + ((u >> 16) & 1u);
  return (ushort)(u >> 16);
}

// fp16-roundtripped gumbel — BIT-IDENTICAL to the old table path.
__device__ __forceinline__ float gumbel_h2f(uint32_t f) {
  return h2f(f2h(gumbel_ref(f)));
}

// bucket = bf16 code (monotone & injective for positive floats); every bucket
// holds only exactly-equal values => scatter position IS the exact rank.
__device__ __forceinline__ int bucket_code(ushort code) {
  return min(max((int)code - 0x4000, 0), BUCKETS - 1);
}

// monotone u32 key for f32 (total order, matches > on non-NaN floats)
__device__ __forceinline__ uint32_t fkey(float f) {
  uint32_t b = __float_as_uint(f);
  return b ^ ((uint32_t)((int32_t)b >> 31) | 0x80000000u);
}

// branchless insert into sorted-descending u64 triple with f32 payload
__device__ __forceinline__ void ins3p(uint64_t v, float s,
                                      uint64_t& t0, float& s0,
                                      uint64_t& t1, float& s1,
                                      uint64_t& t2, float& s2) {
  bool c0 = v > t0, c1 = v > t1, c2 = v > t2;
  t2 = c1 ? t1 : (c2 ? v : t2); s2 = c1 ? s1 : (c2 ? s : s2);
  t1 = c0 ? t0 : (c1 ? v : t1); s1 = c0 ? s0 : (c1 ? s : s1);
  t0 = c0 ? v : t0;             s0 = c0 ? s : s0;
}

// merge two sorted-descending triples (with f32 payload) -> top-3 in a*
__device__ __forceinline__ void merge3p(uint64_t& a0, float& p0,
                                        uint64_t& a1, float& p1,
                                        uint64_t& a2, float& p2,
                                        uint64_t b0, float q0,
                                        uint64_t b1, float q1,
                                        uint64_t b2, float q2) {
  bool sw = b0 > a0;
  uint64_t n0 = sw ? b0 : a0; float n0p = sw ? q0 : p0;
  uint64_t m0 = sw ? a0 : b0; float m0p = sw ? p0 : q0;
  uint64_t n1 = sw ? b1 : a1; float n1p = sw ? q1 : p1;
  uint64_t m1 = sw ? a1 : b1; float m1p = sw ? p1 : q1;
  uint64_t n2 = sw ? b2 : a2; float n2p = sw ? q2 : p2;
  a0 = n0; p0 = n0p;
  bool c = n1 > m0;  // keys distinct (unique ranks)
  a1 = c ? n1 : m0;  p1 = c ? n1p : m0p;
  uint64_t u = c ? n2 : n1; float up = c ? n2p : n1p;
  uint64_t w = c ? m0 : m1; float wp = c ? m0p : m1p;
  bool d = u > w;
  a2 = d ? u : w; p2 = d ? up : wp;
}

// ---------------- kernel A: sumsq + fp32->bf16 convert (4 rows/block) -------
__global__ __launch_bounds__(256) void prep_kernel(const float* __restrict__ X,
                                                   float* __restrict__ sq,
                                                   ushort* __restrict__ Xbf) {
  const int tid = threadIdx.x;
  const int lane = tid & 63;
  const int i = (blockIdx.x << 2) + (tid >> 6);
  float2 v = ((const float2*)(X + (size_t)i * NDIM))[lane];
  float s = v.x * v.x + v.y * v.y;
  for (int o = 32; o > 0; o >>= 1) s += __shfl_down(s, o);
  if (lane == 0) sq[i] = s;
  ushort2 h;
  h.x = f2bf(v.x);
  h.y = f2bf(v.y);
  ((ushort2*)(Xbf + (size_t)i * NDIM))[lane] = h;
}

// ---------------- kernel B: 64x128 staged dist tile per block ---------------
// Same staging/MFMA/epilogue structure as the proven 128x128 version, with the
// A-tile halved (mt<4): LDS 34.8->25.5 KB => 6 blocks/CU (24 waves/CU, +50%
// co-residency), acc VGPRs halved, 2048 blocks for smoother tail. Fragment
// bytes and accumulation order per output element are unchanged =>
// bit-identical distb.
__global__ __launch_bounds__(256) void dist_kernel(const ushort* __restrict__ Xbf,
                                                   const float* __restrict__ sq,
                                                   ushort* __restrict__ distb) {
  __shared__ ushort Als[64 * DSTR];
  __shared__ ushort Bls[128 * DSTR];
  const int tid = threadIdx.x;
  const int bi = blockIdx.x >> 5, bj = blockIdx.x & 31;   // 64 x 32
  const int wave = tid >> 6, lane = tid & 63;
  const int q = lane >> 4, ln = lane & 15;
  const ushort* Ag = Xbf + (size_t)bi * 64 * NDIM;
  const ushort* Bg = Xbf + (size_t)bj * 128 * NDIM;

  f32x4 acc[4][2];
#pragma unroll
  for (int mt = 0; mt < 4; ++mt)
#pragma unroll
    for (int nt = 0; nt < 2; ++nt) acc[mt][nt] = (f32x4){0.f, 0.f, 0.f, 0.f};

  for (int kh = 0; kh < 2; ++kh) {
    if (kh) __syncthreads();
#pragma unroll
    for (int t = 0; t < 2; ++t) {           // A: 64 rows x 64 ks
      int c = tid + 256 * t;
      int r = c >> 3, k8 = (c & 7) << 3;
      *(short8*)&Als[r * DSTR + k8] =
          *(const short8*)(Ag + (size_t)r * NDIM + kh * 64 + k8);
    }
#pragma unroll
    for (int t = 0; t < 4; ++t) {           // B: 128 rows x 64 ks
      int c = tid + 256 * t;
      int r = c >> 3, k8 = (c & 7) << 3;
      *(short8*)&Bls[r * DSTR + k8] =
          *(const short8*)(Bg + (size_t)r * NDIM + kh * 64 + k8);
    }
    __syncthreads();
#pragma unroll
    for (int k0 = 0; k0 < 64; k0 += 32) {
      int kf = k0 + q * 8;
      short8 a[4], b[2];
#pragma unroll
      for (int mt = 0; mt < 4; ++mt)
        a[mt] = *(const short8*)&Als[(mt * 16 + ln) * DSTR + kf];
      // lane owns ADJACENT cols 2*ln, 2*ln+1 -> packed bf16x2 dword stores
#pragma unroll
      for (int nt = 0; nt < 2; ++nt)
        b[nt] = *(const short8*)&Bls[(wave * 32 + 2 * ln + nt) * DSTR + kf];
#pragma unroll
      for (int mt = 0; mt < 4; ++mt)
#pragma unroll
        for (int nt = 0; nt < 2; ++nt)
          acc[mt][nt] = __builtin_amdgcn_mfma_f32_16x16x32_bf16(
              a[mt], b[nt], acc[mt][nt], 0, 0, 0);
    }
  }

  const int jcol = bj * 128 + wave * 32 + 2 * ln;
  float sqj0 = sq[jcol], sqj1 = sq[jcol + 1];
#pragma unroll
  for (int mt = 0; mt < 4; ++mt) {
    int ibase = bi * 64 + mt * 16 + q * 4;
#pragma unroll
    for (int r = 0; r < 4; ++r) {
      int i = ibase + r;
      float sqi = sq[i];
      float dx = sqrtf(fmaxf(sqi + sqj0 - 2.0f * acc[mt][0][r], 1e-12f));
      float dy = sqrtf(fmaxf(sqi + sqj1 - 2.0f * acc[mt][1][r], 1e-12f));
      uint32_t pack = ((uint32_t)f2bf(dy) << 16) | (uint32_t)f2bf(dx);
      *(uint32_t*)(distb + (size_t)i * NROW + jcol) = pack;
    }
  }
}

// ---------------- kernel C: per-row rank + sample + loss --------------------
// Direct-rank scoring: p = base[bkt] + ord; gumbel inline (bit-identical
// fp16 roundtrip); u64 (score,rank) keys; single-pass block top-3.
__global__ __launch_bounds__(256) void row_kernel(const ushort* __restrict__ distb,
                                                  float4* __restrict__ part) {
  __shared__ alignas(16) int base[BUCKETS];    // 8 KB (bucket starts)
  __shared__ alignas(16) float candx[768];     // 3 KB payload
  __shared__ float wredf[8];
  __shared__ int wtot[4];
  __shared__ float s_pos[3];
  __shared__ float s_selx[3];

  // alias — live only after the score pass (base dead after its last read)
  uint64_t* cand = (uint64_t*)base;            // 768 * 8B = 6 KB

  const int i = blockIdx.x;
  const int tid = threadIdx.x;
  const int lane = tid & 63, wid = tid >> 6;
  const ushort* row = distb + (size_t)i * NROW;
  const int gbase = i & ~3;
  const uint32_t fbase = (uint32_t)i * (uint32_t)KNEG;

  {
    int4* b4 = (int4*)base;
    b4[tid] = (int4){0, 0, 0, 0};
    b4[tid + 256] = (int4){0, 0, 0, 0};
  }

  short8 r0 = *(const short8*)(row + tid * 16);
  short8 r1 = *(const short8*)(row + tid * 16 + 8);

  ushort cd[16];
  float x[16];
#pragma unroll
  for (int k = 0; k < 8; ++k) {
    cd[k] = (ushort)r0[k];     x[k] = bf2f(cd[k]);
    cd[8 + k] = (ushort)r1[k]; x[8 + k] = bf2f(cd[8 + k]);
  }

  if (tid == (gbase >> 4)) {
    float p[3]; int np = 0;
#pragma unroll
    for (int qq = 0; qq < 4; ++qq) {
      int j = gbase + qq;
      if (j != i) p[np++] = x[j & 15];
    }
    float a = p[0], b = p[1], c = p[2], t_;
    if (a > b) { t_ = a; a = b; b = t_; }
    if (b > c) { t_ = b; b = c; c = t_; }
    if (a > b) { t_ = a; a = b; b = t_; }
    s_pos[0] = a; s_pos[1] = b; s_pos[2] = c;
  }

#pragma unroll
  for (int qq = 0; qq < 16; ++qq) {
    int j = tid * 16 + qq;
    if ((j >> 2) == (i >> 2)) { x[qq] = INF_VAL; cd[qq] = 0x7F80u; }
  }
  __syncthreads();

  int bkt[16];
  int ord[16];
  float ls = 0.f;
#pragma unroll
  for (int qq = 0; qq < 16; ++qq) {
    bkt[qq] = bucket_code(cd[qq]);
    ord[qq] = atomicAdd(&base[bkt[qq]], 1);
    if (x[qq] < 1e29f) ls += x[qq];
  }
  for (int o = 32; o > 0; o >>= 1) ls += __shfl_down(ls, o);
  if (lane == 0) wredf[wid] = ls;
  __syncthreads();
  const float negsum = wredf[0] + wredf[1] + wredf[2] + wredf[3];
  const float mean = negsum / (float)KNEG;

  int c8[8]; int lsum = 0;
#pragma unroll
  for (int qq = 0; qq < 8; ++qq) {
    int t_ = base[tid * 8 + qq];
    c8[qq] = lsum; lsum += t_;
  }
  float ls2 = 0.f;
#pragma unroll
  for (int qq = 0; qq < 16; ++qq)
    if (x[qq] < 1e29f) { float z = x[qq] - mean; ls2 += z * z; }
  int incl = lsum;
  for (int off = 1; off < 64; off <<= 1) {
    int o = __shfl_up(incl, off);
    if (lane >= off) incl += o;
  }
  for (int o = 32; o > 0; o >>= 1) ls2 += __shfl_down(ls2, o);
  if (lane == 63) wtot[wid] = incl;
  if (lane == 0) wredf[4 + wid] = ls2;
  __syncthreads();
  const float var = (wredf[4] + wredf[5] + wredf[6] + wredf[7]) / (float)KNEG;
  const float stdv = sqrtf(var);
  const float rdenom = __frcp_rn(2.0f * stdv * stdv);
  int excl = incl - lsum;
#pragma unroll
  for (int w = 0; w < 4; ++w) if (w < wid) excl += wtot[w];
#pragma unroll
  for (int qq = 0; qq < 8; ++qq) base[tid * 8 + qq] = excl + c8[qq];
  __syncthreads();

  // ---- score/top-3 directly from registers: p = base[bkt] + ord ----
  uint64_t t0 = 0, t1 = 0, t2 = 0;  // 0 < key of any real candidate
  float t0x = 0.f, t1x = 0.f, t2x = 0.f;
#pragma unroll
  for (int qq = 0; qq < 16; ++qq) {
    if (x[qq] < 1e29f) {                       // reals == ranks 0..KNEG-1
      int p = base[bkt[qq]] + ord[qq];
      float xv = x[qq];
      float z = xv - mean;
      float gv = gumbel_h2f(fbase + (uint32_t)p);
      float sv = fmaf(z * z, rdenom, gv);
      uint64_t v = ((uint64_t)fkey(sv) << 32) | (uint32_t)(8192 - p);
      ins3p(v, xv, t0, t0x, t1, t1x, t2, t2x);
    }
  }
  __syncthreads();  // base reads done; cand alias becomes live

  cand[tid * 3 + 0] = t0; candx[tid * 3 + 0] = t0x;
  cand[tid * 3 + 1] = t1; candx[tid * 3 + 1] = t1x;
  cand[tid * 3 + 2] = t2; candx[tid * 3 + 2] = t2x;
  __syncthreads();

  // ---- single-pass block top-3: wave 0 scans 768 + shfl_xor triple-merge ---
  if (wid == 0) {
    uint64_t a0 = 0, a1 = 0, a2 = 0;
    int i0 = 0, i1 = 0, i2 = 0;
#pragma unroll
    for (int k = 0; k < 12; ++k) {
      int idx = lane + 64 * k;
      uint64_t v = cand[idx];
      bool c0 = v > a0, c1 = v > a1, c2 = v > a2;
      a2 = c1 ? a1 : (c2 ? v : a2); i2 = c1 ? i1 : (c2 ? idx : i2);
      a1 = c0 ? a0 : (c1 ? v : a1); i1 = c0 ? i0 : (c1 ? idx : i1);
      a0 = c0 ? v : a0;             i0 = c0 ? idx : i0;
    }
    float p0 = candx[i0], p1 = candx[i1], p2 = candx[i2];
#pragma unroll
    for (int m = 32; m > 0; m >>= 1) {
      uint64_t b0 = __shfl_xor((unsigned long long)a0, m);
      uint64_t b1 = __shfl_xor((unsigned long long)a1, m);
      uint64_t b2 = __shfl_xor((unsigned long long)a2, m);
      float q0 = __shfl_xor(p0, m);
      float q1 = __shfl_xor(p1, m);
      float q2 = __shfl_xor(p2, m);
      merge3p(a0, p0, a1, p1, a2, p2, b0, q0, b1, q1, b2, q2);
    }
    if (lane == 0) {
      s_selx[0] = p0; s_selx[1] = p1; s_selx[2] = p2;
    }
  }
  __syncthreads();

  if (tid == 0) {
    float p0 = s_pos[0], p1 = s_pos[1], p2 = s_pos[2];
    float thr = p2 + 0.05f;
    float samp[3]; bool kept[3]; int cnt = 0;
#pragma unroll
    for (int t = 0; t < 3; ++t) {
      samp[t] = s_selx[t];
      kept[t] = samp[t] < thr;
      cnt += kept[t] ? 1 : 0;
    }
    bool any = cnt > 0;
    float pos_loss = 0.5f *
        (softplus_ref(-2.0f * (1.0f - p0)) + softplus_ref(-2.0f * (1.0f - p1)) +
         softplus_ref(-2.0f * (1.0f - p2))) / 3.0f;
    float nsum = 0.0f;
#pragma unroll
    for (int t = 0; t < 3; ++t)
      if (kept[t]) nsum += softplus_ref(20.0f * (1.0f - samp[t]));
    float neg_loss = 0.05f * nsum / (float)(cnt > 0 ? cnt : 1);
    float row_loss = any ? (pos_loss + neg_loss) : 0.0f;
    int first = kept[0] ? 0 : (kept[1] ? 1 : (kept[2] ? 2 : 0));
    float neg0 = samp[first];
    float errv = (any && (p0 < neg0 - 0.1f)) ? 1.0f : 0.0f;
    float4 pr;
    pr.x = row_loss; pr.y = errv; pr.z = p0 + p1 + p2; pr.w = negsum;
    part[i] = pr;
  }
}

// ---------------- reduce: 4096 float4 partials -> 4 outputs ----------------
__global__ __launch_bounds__(256) void reduce_kernel(const float4* __restrict__ part,
                                                     float* __restrict__ out) {
  __shared__ double wsum[4][4];
  const int tid = threadIdx.x;
  const int lane = tid & 63, wid = tid >> 6;
  double s0 = 0.0, s1 = 0.0, s2 = 0.0, s3 = 0.0;
  for (int k = tid; k < NROW; k += 256) {
    float4 v = part[k];
    s0 += (double)v.x; s1 += (double)v.y; s2 += (double)v.z; s3 += (double)v.w;
  }
  for (int o = 32; o > 0; o >>= 1) {
    s0 += __shfl_down(s0, o); s1 += __shfl_down(s1, o);
    s2 += __shfl_down(s2, o); s3 += __shfl_down(s3, o);
  }
  if (lane == 0) {
    wsum[wid][0] = s0; wsum[wid][1] = s1; wsum[wid][2] = s2; wsum[wid][3] = s3;
  }
  __syncthreads();
  if (tid == 0) {
    double a0 = wsum[0][0] + wsum[1][0] + wsum[2][0] + wsum[3][0];
    double a1 = wsum[0][1] + wsum[1][1] + wsum[2][1] + wsum[3][1];
    double a2 = wsum[0][2] + wsum[1][2] + wsum[2][2] + wsum[3][2];
    double a3 = wsum[0][3] + wsum[1][3] + wsum[2][3] + wsum[3][3];
    out[0] = (float)(a0 / (double)NROW);
    out[1] = (float)(1.0 - a1 / (double)NROW);
    out[2] = (float)(a2 / ((double)NROW * 3.0));
    out[3] = (float)(a3 / ((double)NROW * (double)KNEG));
  }
}

extern "C" void kernel_launch(void* const* d_in, const int* in_sizes, int n_in,
                              void* d_out, int out_size, void* d_ws, size_t ws_size,
                              hipStream_t stream) {
  (void)in_sizes; (void)n_in; (void)out_size; (void)ws_size;
  const float* X = (const float*)d_in[0];
  float* out = (float*)d_out;
  char* ws = (char*)d_ws;

  ushort* distb = (ushort*)ws;                                     // 32 MiB bf16
  size_t off = (size_t)NROW * NROW * sizeof(ushort);
  float* sq = (float*)(ws + off);            off += NROW * sizeof(float);
  ushort* Xbf = (ushort*)(ws + off);         off += (size_t)NROW * NDIM * sizeof(ushort);
  float4* part = (float4*)(ws + off);        off += (size_t)NROW * sizeof(float4);

  prep_kernel<<<NROW / 4, 256, 0, stream>>>(X, sq, Xbf);
  dist_kernel<<<DISTBLKS, 256, 0, stream>>>(Xbf, sq, distb);
  row_kernel<<<NROW, 256, 0, stream>>>(distb, part);
  reduce_kernel<<<1, 256, 0, stream>>>(part, out);
}